// Round 13
// baseline (159.476 us; speedup 1.0000x reference)
//
#include <hip/hip_runtime.h>
#include <hip/hip_bf16.h>
#include <stdint.h>

#define B_  2
#define S_  2048
#define D_  1024
#define H_  16
#define HD_ 64

typedef __attribute__((ext_vector_type(8)))  __bf16 bf16x8;
typedef __attribute__((ext_vector_type(4)))  __bf16 bf16x4;
typedef __attribute__((ext_vector_type(2)))  __bf16 bf16x2;
typedef __attribute__((ext_vector_type(2)))  float  f32x2;
typedef __attribute__((ext_vector_type(4)))  float  f32x4;
typedef __attribute__((ext_vector_type(16))) float  f32x16;
typedef __attribute__((ext_vector_type(4)))  uint32_t u32x4;

// 0.125 * log2(e): folded into Q so attention scores feed exp2 directly.
#define QSCALE 0.18033688011112042f

__device__ __forceinline__ void gload16(const void* g, void* l) {
  __builtin_amdgcn_global_load_lds(
      (__attribute__((address_space(1))) void*)(uintptr_t)g,
      (__attribute__((address_space(3))) void*)(uintptr_t)l,
      16, 0, 0);
}

// NOTE (R4): v_cvt_pk_bf16_f32 packing FAILED accuracy; keep +0x8000+v_perm.
// NOTE (R6): fused butterfly/atomic epilogue failed accuracy; po/pl+attn2 is
// the proven path.
// NOTE (R8): 2x occupancy neutral -> attn1 not TLP-bound.
// NOTE (R11): fragment-order vt + b128 V-frag reads VERIFIED (conflicts
// 3.1M->2.1M, attn1 47.5->45.4). NOTE (R12): coalesced gemm epilogue VERIFIED
// (total 160.7->157.8).
// R13 theory: attn1 idle accounting (MFMA 32.7k + VALU 42.5k of 109k cycles,
// 34k both-idle) + barrier phase-alignment of all waves explains R3/R7/R8
// nulls. This round: odd waves process st1 before st0 (anti-phase) so one
// wave's VALU phase overlaps the other's MFMA phase. attn2: bf16x2 loads.

// ---------------- fused prep: zero out / convert X / transpose W ----------------
__global__ __launch_bounds__(256) void prep(
    const float* __restrict__ x, const float* __restrict__ wq,
    const float* __restrict__ wk, const float* __restrict__ wv,
    __bf16* __restrict__ xb, __bf16* __restrict__ wt, float* __restrict__ out) {
  __shared__ float tile[32][33];
  const int t = threadIdx.x;
  const int bx = blockIdx.x;
  if (bx < 4096) {
    int i = bx * 256 + t;
    float4 v = ((const float4*)x)[i];
    bf16x4 o;
    o[0] = (__bf16)v.x; o[1] = (__bf16)v.y; o[2] = (__bf16)v.z; o[3] = (__bf16)v.w;
    ((bf16x4*)xb)[i] = o;
  } else if (bx < 7168) {
    int tb = bx - 4096;
    int z = tb >> 10;
    int rem = tb & 1023;
    int n0 = (rem & 31) * 32, k0 = (rem >> 5) * 32;
    const float* w = (z == 0) ? wq : (z == 1 ? wk : wv);
    __bf16* o = wt + (size_t)z * D_ * D_;
    int tx = t & 31, ty = t >> 5;
    for (int i = 0; i < 4; ++i)
      tile[ty + 8 * i][tx] = w[(size_t)(k0 + ty + 8 * i) * D_ + n0 + tx];
    __syncthreads();
    for (int i = 0; i < 4; ++i)
      o[(size_t)(n0 + ty + 8 * i) * D_ + k0 + tx] = (__bf16)tile[tx][ty + 8 * i];
  } else {
    float4* o4 = (float4*)out;
    float4 z4 = {0.f, 0.f, 0.f, 0.f};
    o4[t] = z4;
    o4[t + 256] = z4;
  }
}

// ---------------- QKV GEMM, 128x128, BK=32, dbuf; coalesced epilogue ----------------
// R12-verified: LDS re-stage epilogue -> contiguous 128B/256B row writes.
// vt keeps R9's fragment-order slot permutation (quadv).
__global__ __launch_bounds__(256, 3) void gemm_qkv(
    const __bf16* __restrict__ xb, const __bf16* __restrict__ wt,
    const float* __restrict__ bq, const float* __restrict__ bk,
    const float* __restrict__ bv, __bf16* __restrict__ qh,
    __bf16* __restrict__ kh, __bf16* __restrict__ vt) {
  constexpr int K = 1024;
  constexpr int NIT = K / 32;
  constexpr int PITCH = 136;  // elems; 272B rows, 16B-aligned
  __shared__ __attribute__((aligned(16))) char smem[34816];
  auto lA = [&](int buf) -> char* { return smem + buf * 8192; };
  auto lB = [&](int buf) -> char* { return smem + 16384 + buf * 8192; };
  __bf16* epi = (__bf16*)smem;  // epilogue tile, reused after final barrier

  const int z = blockIdx.z;
  const __bf16* w = wt + (size_t)z * K * D_;
  const float* bias = (z == 0) ? bq : (z == 1 ? bk : bv);
  const int t = threadIdx.x;
  const int lane = t & 63;
  const int wid = t >> 6;
  const int quad = lane >> 4;
  const int col = lane & 15;
  const int m0 = blockIdx.x * 128;
  const int n0 = blockIdx.y * 128;
  const int wr = (wid >> 1) * 64;
  const int wc = (wid & 1) * 64;

  const int sr0 = t >> 2;
  const int gc = (t & 3) ^ ((t >> 2) & 3);

  auto stage = [&](int kt, int buf) {
    gload16(xb + (size_t)(m0 + sr0) * K + kt * 32 + gc * 8, lA(buf) + t * 16);
    gload16(xb + (size_t)(m0 + 64 + sr0) * K + kt * 32 + gc * 8,
            lA(buf) + 4096 + t * 16);
    gload16(w + (size_t)(n0 + sr0) * K + kt * 32 + gc * 8, lB(buf) + t * 16);
    gload16(w + (size_t)(n0 + 64 + sr0) * K + kt * 32 + gc * 8,
            lB(buf) + 4096 + t * 16);
  };

  f32x4 acc[4][4] = {};

  stage(0, 0);

  if (z < 2) {
    for (int kt = 0; kt < NIT; ++kt) {
      const int cur = kt & 1;
      __syncthreads();
      if (kt + 1 < NIT) stage(kt + 1, cur ^ 1);
      bf16x8 fw[4], fx[4];
      for (int i = 0; i < 4; ++i) {
        int n = wr + i * 16 + col;
        int sl = quad ^ (n & 3);
        fw[i] = *(const bf16x8*)(lB(cur) + n * 64 + sl * 16);
      }
      for (int j = 0; j < 4; ++j) {
        int m = wc + j * 16 + col;
        int sl = quad ^ (m & 3);
        fx[j] = *(const bf16x8*)(lA(cur) + m * 64 + sl * 16);
      }
      for (int i = 0; i < 4; ++i)
        for (int j = 0; j < 4; ++j)
          acc[i][j] = __builtin_amdgcn_mfma_f32_16x16x32_bf16(
              fw[i], fx[j], acc[i][j], 0, 0, 0);
    }
    // ---- epilogue: acc -> LDS [m][n], then coalesced row stores ----
    __syncthreads();  // all waves done reading lA/lB; reuse as epi
    const float scale = (z == 0) ? QSCALE : 1.0f;
    for (int i = 0; i < 4; ++i) {
      int gnb = n0 + wr + i * 16 + quad * 4;
      float4 bi = *(const float4*)(bias + gnb);
      const int nl = wr + i * 16 + quad * 4;
      for (int j = 0; j < 4; ++j) {
        const int ml = wc + j * 16 + col;
        bf16x4 pk;
        pk[0] = (__bf16)((acc[i][j][0] + bi.x) * scale);
        pk[1] = (__bf16)((acc[i][j][1] + bi.y) * scale);
        pk[2] = (__bf16)((acc[i][j][2] + bi.z) * scale);
        pk[3] = (__bf16)((acc[i][j][3] + bi.w) * scale);
        *(bf16x4*)(epi + (size_t)ml * PITCH + nl) = pk;
      }
    }
    __syncthreads();
    __bf16* dst = (z == 0) ? qh : kh;
    const int b = m0 >> 11;
    const int h0 = n0 >> 6;
    const int sb = m0 & 2047;
    for (int k = 0; k < 8; ++k) {
      int g = k * 32 + (t >> 3);
      int h2 = g >> 7, sl2 = g & 127;
      int c = t & 7;
      bf16x8 v = *(const bf16x8*)(epi + (size_t)sl2 * PITCH + h2 * 64 + c * 8);
      *(bf16x8*)(dst + ((size_t)(b * H_ + h0 + h2) * S_ + sb + sl2) * HD_ +
                 c * 8) = v;
    }
  } else {
    for (int kt = 0; kt < NIT; ++kt) {
      const int cur = kt & 1;
      __syncthreads();
      if (kt + 1 < NIT) stage(kt + 1, cur ^ 1);
      bf16x8 fx[4], fw[4];
      for (int i = 0; i < 4; ++i) {
        int m = wr + i * 16 + col;
        int sl = quad ^ (m & 3);
        fx[i] = *(const bf16x8*)(lA(cur) + m * 64 + sl * 16);
      }
      for (int j = 0; j < 4; ++j) {
        int n = wc + j * 16 + col;
        int sl = quad ^ (n & 3);
        fw[j] = *(const bf16x8*)(lB(cur) + n * 64 + sl * 16);
      }
      for (int i = 0; i < 4; ++i)
        for (int j = 0; j < 4; ++j)
          acc[i][j] = __builtin_amdgcn_mfma_f32_16x16x32_bf16(
              fx[i], fw[j], acc[i][j], 0, 0, 0);
    }
    // ---- epilogue: acc -> LDS [n][m] in R9 fragment order, coalesced stores ----
    __syncthreads();
    const int quadv = ((quad & 1) << 1) | ((quad >> 1) & 1);  // R9 involution
    for (int i = 0; i < 4; ++i) {
      const int ml = wr + i * 16 + quadv * 4;  // fragment-order m slot
      for (int j = 0; j < 4; ++j) {
        int gn = n0 + wc + j * 16 + col;
        const int nl = wc + j * 16 + col;
        float bi = bias[gn];
        bf16x4 pk;
        pk[0] = (__bf16)(acc[i][j][0] + bi);
        pk[1] = (__bf16)(acc[i][j][1] + bi);
        pk[2] = (__bf16)(acc[i][j][2] + bi);
        pk[3] = (__bf16)(acc[i][j][3] + bi);
        *(bf16x4*)(epi + (size_t)nl * PITCH + ml) = pk;
      }
    }
    __syncthreads();
    const int b = m0 >> 11;
    const int sb = m0 & 2047;
    for (int k = 0; k < 8; ++k) {
      int nl = k * 16 + (t >> 4);
      int c = t & 15;
      bf16x8 v = *(const bf16x8*)(epi + (size_t)nl * PITCH + c * 8);
      int h = (n0 + nl) >> 6, hd = (n0 + nl) & 63;
      *(bf16x8*)(vt + ((size_t)(b * H_ + h) * HD_ + hd) * S_ + sb + c * 8) = v;
    }
  }
}

// ---------------- attention phase 1: anti-phased waves ----------------
// grid (bh=32, qblk=8, kc=2) = 512 blocks = 2/CU; XCD = bh%8.
// R13: odd waves run the st=1 sub-tile first. Identical work; one wave's
// softmax-VALU phase now coincides with the other's QK/PV-MFMA phase between
// barriers, enabling cross-pipe overlap the lockstep schedule forbade
// (explains R3 setprio null: no phase diversity existed to arbitrate).
// st passed as literal through a lambda -> all array indices compile-time
// (rule #20: runtime-indexed ext_vector arrays spill to scratch).
// NOTE (R1): never cap regs at 128 (spill -> 3GB/disp scratch streamer).
__global__ __launch_bounds__(256, 2) void attn1(
    const __bf16* __restrict__ qh, const __bf16* __restrict__ kh,
    const __bf16* __restrict__ vt, __bf16* __restrict__ po,
    float* __restrict__ pl) {
  __shared__ __attribute__((aligned(16))) __bf16 lK[2][64 * 64];  // [sk][hd] swz
  __shared__ __attribute__((aligned(16))) __bf16 lV[2][64 * 64];  // [hd][sk-frag] swz

  const int t = threadIdx.x;
  const int lane = t & 63;
  const int half = lane >> 5;
  const int q31 = lane & 31;
  const int wid = t >> 6;
  const int bh = blockIdx.x;
  const int kc = blockIdx.z;
  const int q0w = blockIdx.y * 256 + wid * 64;  // wave's 64 q rows

  const __bf16* qbase = qh + (size_t)bh * S_ * HD_;
  const __bf16* kbase = kh + (size_t)bh * S_ * HD_;
  const __bf16* vbase = vt + (size_t)bh * HD_ * S_;

  // Q as B-frags: B[n=q=lane&31][k=16ks+8*half+j], per q-tile
  bf16x8 aq[2][4];
  for (int qt = 0; qt < 2; ++qt)
    for (int ks = 0; ks < 4; ++ks)
      aq[qt][ks] = *(const bf16x8*)(qbase +
          (size_t)(q0w + qt * 32 + q31) * HD_ + ks * 16 + half * 8);

  f32x16 o[2][2] = {};  // [qt][hdt]
  f32x2 ls[2] = {{0.f, 0.f}, {0.f, 0.f}};

  const int srow = t >> 3;                  // 0..31
  const int sgc = (t & 7) ^ (srow & 7);     // swizzled global chunk

  auto stage = [&](int kt, int buf) {
    gload16(kbase + (size_t)(kt * 64 + srow) * HD_ + sgc * 8,
            (char*)&lK[buf][0] + t * 16);
    gload16(kbase + (size_t)(kt * 64 + 32 + srow) * HD_ + sgc * 8,
            (char*)&lK[buf][0] + 4096 + t * 16);
    gload16(vbase + (size_t)srow * S_ + kt * 64 + sgc * 8,
            (char*)&lV[buf][0] + t * 16);
    gload16(vbase + (size_t)(32 + srow) * S_ + kt * 64 + sgc * 8,
            (char*)&lV[buf][0] + 4096 + t * 16);
  };

  stage(kc * 16, 0);

  for (int kt0 = 0; kt0 < 16; ++kt0) {
    const int cur = kt0 & 1;
    __syncthreads();  // drains vmcnt: buf[cur] staged; all done reading buf[cur^1]
    if (kt0 + 1 < 16) stage(kc * 16 + kt0 + 1, cur ^ 1);

    // ---- hoisted LDS reads: everything this iteration needs ----
    bf16x8 fk[2][4];       // [st][ks]
    bf16x8 av[2][2][2];    // [st][hdt][k2] V^T A-frags (b128, frag-ordered vt)
#pragma unroll
    for (int st = 0; st < 2; ++st) {
      const int row = st * 32 + q31;
#pragma unroll
      for (int ks = 0; ks < 4; ++ks) {
        int pos = (2 * ks + half) ^ (row & 7);
        fk[st][ks] = *(const bf16x8*)((const char*)&lK[cur][0] + row * 128 + pos * 16);
      }
    }
#pragma unroll
    for (int st = 0; st < 2; ++st)
#pragma unroll
      for (int hdt = 0; hdt < 2; ++hdt) {
        const int rowv = hdt * 32 + q31;
#pragma unroll
        for (int k2 = 0; k2 < 2; ++k2) {
          int pos = (st * 4 + k2 * 2 + half) ^ (rowv & 7);
          av[st][hdt][k2] = *(const bf16x8*)((const char*)&lV[cur][0] + rowv * 128 +
                                             pos * 16);
        }
      }

    auto subtile = [&](int st) {
      // S^T tiles for both q-tiles; each fk feeds two MFMAs
      f32x16 sc0 = {}, sc1 = {};
#pragma unroll
      for (int ks = 0; ks < 4; ++ks) {
        sc0 = __builtin_amdgcn_mfma_f32_32x32x16_bf16(fk[st][ks], aq[0][ks], sc0, 0, 0, 0);
        sc1 = __builtin_amdgcn_mfma_f32_32x32x16_bf16(fk[st][ks], aq[1][ks], sc1, 0, 0, 0);
      }

      // exp2 + packed lsum + pack pairs via v_perm (round-half-up), per q-tile
      uint32_t pk0[8], pk1[8];
#pragma unroll
      for (int p = 0; p < 8; ++p) {
        float ea = __builtin_amdgcn_exp2f(sc0[2 * p]);
        float eb = __builtin_amdgcn_exp2f(sc0[2 * p + 1]);
        f32x2 e2 = {ea, eb};
        ls[0] += e2;
        uint32_t au = __builtin_bit_cast(uint32_t, ea) + 0x8000u;
        uint32_t bu = __builtin_bit_cast(uint32_t, eb) + 0x8000u;
        pk0[p] = __builtin_amdgcn_perm(bu, au, 0x07060302u);
      }
#pragma unroll
      for (int p = 0; p < 8; ++p) {
        float ea = __builtin_amdgcn_exp2f(sc1[2 * p]);
        float eb = __builtin_amdgcn_exp2f(sc1[2 * p + 1]);
        f32x2 e2 = {ea, eb};
        ls[1] += e2;
        uint32_t au = __builtin_bit_cast(uint32_t, ea) + 0x8000u;
        uint32_t bu = __builtin_bit_cast(uint32_t, eb) + 0x8000u;
        pk1[p] = __builtin_amdgcn_perm(bu, au, 0x07060302u);
      }

      // P B-frags, K=16 (k-map k(h,j) = 8*(j>>2) + 4h + (j&3), matches av)
      u32x4 w;
      w[0] = pk0[0]; w[1] = pk0[1]; w[2] = pk0[2]; w[3] = pk0[3];
      bf16x8 fp0a = __builtin_bit_cast(bf16x8, w);
      w[0] = pk0[4]; w[1] = pk0[5]; w[2] = pk0[6]; w[3] = pk0[7];
      bf16x8 fp0b = __builtin_bit_cast(bf16x8, w);
      w[0] = pk1[0]; w[1] = pk1[1]; w[2] = pk1[2]; w[3] = pk1[3];
      bf16x8 fp1a = __builtin_bit_cast(bf16x8, w);
      w[0] = pk1[4]; w[1] = pk1[5]; w[2] = pk1[6]; w[3] = pk1[7];
      bf16x8 fp1b = __builtin_bit_cast(bf16x8, w);

      // O^T += V^T · P^T, K=16 per MFMA
#pragma unroll
      for (int hdt = 0; hdt < 2; ++hdt) {
        o[0][hdt] = __builtin_amdgcn_mfma_f32_32x32x16_bf16(av[st][hdt][0], fp0a, o[0][hdt], 0, 0, 0);
        o[1][hdt] = __builtin_amdgcn_mfma_f32_32x32x16_bf16(av[st][hdt][0], fp1a, o[1][hdt], 0, 0, 0);
        o[0][hdt] = __builtin_amdgcn_mfma_f32_32x32x16_bf16(av[st][hdt][1], fp0b, o[0][hdt], 0, 0, 0);
        o[1][hdt] = __builtin_amdgcn_mfma_f32_32x32x16_bf16(av[st][hdt][1], fp1b, o[1][hdt], 0, 0, 0);
      }
    };

    // anti-phase: odd waves do st1 first so their MFMA phase overlaps the
    // even waves' softmax-VALU phase (and vice versa). Same math; o/ls
    // accumulation order swaps for odd waves (few-ulp effect only).
    if ((wid & 1) == 0) {
      subtile(0);
      subtile(1);
    } else {
      subtile(1);
      subtile(0);
    }
  }

  // store partials per q-tile: po[(kc*32+bh)][qrow][hd] bf16 (8B), pl fp32
  const size_t slab = (size_t)(kc * 32 + bh) * S_;
  for (int qt = 0; qt < 2; ++qt) {
    float lq = ls[qt].x + ls[qt].y;
    float ltot = lq + __shfl_xor(lq, 32);
    const int qrow = q0w + qt * 32 + q31;
    if (half == 0) pl[slab + qrow] = ltot;
    for (int hdt = 0; hdt < 2; ++hdt)
      for (int rq = 0; rq < 4; ++rq) {
        bf16x4 pk;
        pk[0] = (__bf16)o[qt][hdt][rq * 4 + 0];
        pk[1] = (__bf16)o[qt][hdt][rq * 4 + 1];
        pk[2] = (__bf16)o[qt][hdt][rq * 4 + 2];
        pk[3] = (__bf16)o[qt][hdt][rq * 4 + 3];
        *(bf16x4*)(po + (slab + qrow) * HD_ + hdt * 32 + rq * 8 + half * 4) = pk;
      }
  }
}

// ---------------- attention phase 2: combine, divide, mean-pool ----------------
// grid (rg=32, bh=32) = 1024 blocks. R13: bf16x2 loads, 2 hd per thread
// (halves the scalar-load instruction count; same per-output add order).
__global__ __launch_bounds__(256) void attn2(const __bf16* __restrict__ po,
                                             const float* __restrict__ pl,
                                             float* __restrict__ out) {
  __shared__ f32x2 red[256];
  const int t = threadIdx.x;
  const int hd2 = (t & 31) * 2;
  const int rgrp = t >> 5;   // 0..7
  const int bh = blockIdx.y;
  const int r0 = blockIdx.x * 64 + rgrp * 8;
  const size_t s0 = (size_t)bh * S_;
  const size_t s1 = (size_t)(32 + bh) * S_;
  f32x2 acc = {0.f, 0.f};
#pragma unroll 8
  for (int i = 0; i < 8; ++i) {
    int row = r0 + i;
    float l = pl[s0 + row] + pl[s1 + row];
    bf16x2 a = *(const bf16x2*)(po + (s0 + row) * HD_ + hd2);
    bf16x2 b = *(const bf16x2*)(po + (s1 + row) * HD_ + hd2);
    acc.x += ((float)a[0] + (float)b[0]) / l;
    acc.y += ((float)a[1] + (float)b[1]) / l;
  }
  red[t] = acc;
  __syncthreads();
  if (t < 32) {
    f32x2 s = red[t];
#pragma unroll
    for (int g = 1; g < 8; ++g) s += red[t + g * 32];
    float* ob = out + (size_t)(bh >> 4) * D_ + (bh & 15) * HD_ + hd2;
    atomicAdd(ob,     s.x * (1.0f / S_));
    atomicAdd(ob + 1, s.y * (1.0f / S_));
  }
}

extern "C" void kernel_launch(void* const* d_in, const int* in_sizes, int n_in,
                              void* d_out, int out_size, void* d_ws, size_t ws_size,
                              hipStream_t stream) {
  const float* x  = (const float*)d_in[0];
  const float* Wq = (const float*)d_in[1];
  const float* bq = (const float*)d_in[2];
  const float* Wk = (const float*)d_in[3];
  const float* bk = (const float*)d_in[4];
  const float* Wv = (const float*)d_in[5];
  const float* bv = (const float*)d_in[6];
  float* out = (float*)d_out;

  char* ws = (char*)d_ws;
  __bf16* qh = (__bf16*)(ws);                       //  0..8 MB
  __bf16* kh = (__bf16*)(ws + ((size_t)8  << 20));  //  8..16 MB
  __bf16* vt = (__bf16*)(ws + ((size_t)16 << 20));  // 16..24 MB
  __bf16* xb = (__bf16*)(ws + ((size_t)24 << 20));  // 24..32 MB (dead after gemm)
  __bf16* wt = (__bf16*)(ws + ((size_t)32 << 20));  // 32..38 MB (dead after gemm)
  __bf16* po = (__bf16*)(ws + ((size_t)24 << 20));  // 24..40 MB (overlays xb/wt)
  float*  pl = (float*) (ws + ((size_t)40 << 20));  // 40..40.5 MB

  prep<<<dim3(7169), dim3(256), 0, stream>>>(x, Wq, Wk, Wv, xb, wt, out);
  gemm_qkv<<<dim3(32, 8, 3), dim3(256), 0, stream>>>(xb, wt, bq, bk, bv, qh, kh, vt);
  attn1<<<dim3(B_ * H_, 8, 2), dim3(256), 0, stream>>>(qh, kh, vt, po, pl);
  attn2<<<dim3(32, B_ * H_), dim3(256), 0, stream>>>(po, pl, out);
}

// Round 14
// 155.070 us; speedup vs baseline: 1.0284x; 1.0284x over previous
//
#include <hip/hip_runtime.h>
#include <hip/hip_bf16.h>
#include <stdint.h>

#define B_  2
#define S_  2048
#define D_  1024
#define H_  16
#define HD_ 64

typedef __attribute__((ext_vector_type(8)))  __bf16 bf16x8;
typedef __attribute__((ext_vector_type(4)))  __bf16 bf16x4;
typedef __attribute__((ext_vector_type(2)))  __bf16 bf16x2;
typedef __attribute__((ext_vector_type(2)))  float  f32x2;
typedef __attribute__((ext_vector_type(4)))  float  f32x4;
typedef __attribute__((ext_vector_type(16))) float  f32x16;
typedef __attribute__((ext_vector_type(4)))  uint32_t u32x4;

// 0.125 * log2(e): folded into Q so attention scores feed exp2 directly.
#define QSCALE 0.18033688011112042f

__device__ __forceinline__ void gload16(const void* g, void* l) {
  __builtin_amdgcn_global_load_lds(
      (__attribute__((address_space(1))) void*)(uintptr_t)g,
      (__attribute__((address_space(3))) void*)(uintptr_t)l,
      16, 0, 0);
}

// NOTE (R4): v_cvt_pk_bf16_f32 packing FAILED accuracy; keep +0x8000+v_perm.
// NOTE (R6): fused butterfly/atomic epilogue failed accuracy; po/pl+attn2 is
// the proven path.
// NOTE (R8): 2x occupancy neutral -> attn1 not TLP-bound.
// NOTE (R11): fragment-order vt + b128 V-frag reads VERIFIED (conflicts
// 3.1M->2.1M, attn1 47.5->45.4). NOTE (R12): coalesced gemm epilogue VERIFIED
// (total 160.7->157.8).
// NOTE (R13): wave anti-phasing REGRESSED attn1 45.2->47.4 (VGPR 116->128,
// 4x inlined body; scheduler already interleaves waves) - reverted. attn2
// bf16x2 vectorization verified correct - kept.
// R14: gemm XCD-ownership grid map. Round-robin gave each XCD 4 A-panels +
// ALL 24 B-panels = 7MB > 4MB L2. New 1D map: XCD c owns an 8x*4y*3z brick
// = 2MB A + 3MB B = 5MB (-30% L2 footprint). Bijective; speed-only change.

// ---------------- fused prep: zero out / convert X / transpose W ----------------
__global__ __launch_bounds__(256) void prep(
    const float* __restrict__ x, const float* __restrict__ wq,
    const float* __restrict__ wk, const float* __restrict__ wv,
    __bf16* __restrict__ xb, __bf16* __restrict__ wt, float* __restrict__ out) {
  __shared__ float tile[32][33];
  const int t = threadIdx.x;
  const int bx = blockIdx.x;
  if (bx < 4096) {
    int i = bx * 256 + t;
    float4 v = ((const float4*)x)[i];
    bf16x4 o;
    o[0] = (__bf16)v.x; o[1] = (__bf16)v.y; o[2] = (__bf16)v.z; o[3] = (__bf16)v.w;
    ((bf16x4*)xb)[i] = o;
  } else if (bx < 7168) {
    int tb = bx - 4096;
    int z = tb >> 10;
    int rem = tb & 1023;
    int n0 = (rem & 31) * 32, k0 = (rem >> 5) * 32;
    const float* w = (z == 0) ? wq : (z == 1 ? wk : wv);
    __bf16* o = wt + (size_t)z * D_ * D_;
    int tx = t & 31, ty = t >> 5;
    for (int i = 0; i < 4; ++i)
      tile[ty + 8 * i][tx] = w[(size_t)(k0 + ty + 8 * i) * D_ + n0 + tx];
    __syncthreads();
    for (int i = 0; i < 4; ++i)
      o[(size_t)(n0 + ty + 8 * i) * D_ + k0 + tx] = (__bf16)tile[tx][ty + 8 * i];
  } else {
    float4* o4 = (float4*)out;
    float4 z4 = {0.f, 0.f, 0.f, 0.f};
    o4[t] = z4;
    o4[t + 256] = z4;
  }
}

// ---------------- QKV GEMM, 128x128, BK=32, dbuf; coalesced epilogue ----------------
// R12-verified epilogue; R14: 1D grid with XCD-ownership decode.
__global__ __launch_bounds__(256, 3) void gemm_qkv(
    const __bf16* __restrict__ xb, const __bf16* __restrict__ wt,
    const float* __restrict__ bq, const float* __restrict__ bk,
    const float* __restrict__ bv, __bf16* __restrict__ qh,
    __bf16* __restrict__ kh, __bf16* __restrict__ vt) {
  constexpr int K = 1024;
  constexpr int NIT = K / 32;
  constexpr int PITCH = 136;  // elems; 272B rows, 16B-aligned
  __shared__ __attribute__((aligned(16))) char smem[34816];
  auto lA = [&](int buf) -> char* { return smem + buf * 8192; };
  auto lB = [&](int buf) -> char* { return smem + 16384 + buf * 8192; };
  __bf16* epi = (__bf16*)smem;  // epilogue tile, reused after final barrier

  // XCD-ownership decode: hardware round-robin assigns XCD = bid%8; XCD c
  // owns k=bid>>3 in [0,96): an 8x * 4y * 3z brick (2MB A + 3MB B in L2).
  const int bid = blockIdx.x;
  const int c = bid & 7, k = bid >> 3;
  const int bx = 8 * (c & 3) + (k & 7);          // m-tile 0..31
  const int by = 4 * (c >> 2) + ((k >> 3) & 3);  // n-tile 0..7
  const int z = k >> 5;                          // 0..2

  const __bf16* w = wt + (size_t)z * K * D_;
  const float* bias = (z == 0) ? bq : (z == 1 ? bk : bv);
  const int t = threadIdx.x;
  const int lane = t & 63;
  const int wid = t >> 6;
  const int quad = lane >> 4;
  const int col = lane & 15;
  const int m0 = bx * 128;
  const int n0 = by * 128;
  const int wr = (wid >> 1) * 64;
  const int wc = (wid & 1) * 64;

  const int sr0 = t >> 2;
  const int gc = (t & 3) ^ ((t >> 2) & 3);

  auto stage = [&](int kt, int buf) {
    gload16(xb + (size_t)(m0 + sr0) * K + kt * 32 + gc * 8, lA(buf) + t * 16);
    gload16(xb + (size_t)(m0 + 64 + sr0) * K + kt * 32 + gc * 8,
            lA(buf) + 4096 + t * 16);
    gload16(w + (size_t)(n0 + sr0) * K + kt * 32 + gc * 8, lB(buf) + t * 16);
    gload16(w + (size_t)(n0 + 64 + sr0) * K + kt * 32 + gc * 8,
            lB(buf) + 4096 + t * 16);
  };

  f32x4 acc[4][4] = {};

  stage(0, 0);

  if (z < 2) {
    for (int kt = 0; kt < NIT; ++kt) {
      const int cur = kt & 1;
      __syncthreads();
      if (kt + 1 < NIT) stage(kt + 1, cur ^ 1);
      bf16x8 fw[4], fx[4];
      for (int i = 0; i < 4; ++i) {
        int n = wr + i * 16 + col;
        int sl = quad ^ (n & 3);
        fw[i] = *(const bf16x8*)(lB(cur) + n * 64 + sl * 16);
      }
      for (int j = 0; j < 4; ++j) {
        int m = wc + j * 16 + col;
        int sl = quad ^ (m & 3);
        fx[j] = *(const bf16x8*)(lA(cur) + m * 64 + sl * 16);
      }
      for (int i = 0; i < 4; ++i)
        for (int j = 0; j < 4; ++j)
          acc[i][j] = __builtin_amdgcn_mfma_f32_16x16x32_bf16(
              fw[i], fx[j], acc[i][j], 0, 0, 0);
    }
    // ---- epilogue: acc -> LDS [m][n], then coalesced row stores ----
    __syncthreads();  // all waves done reading lA/lB; reuse as epi
    const float scale = (z == 0) ? QSCALE : 1.0f;
    for (int i = 0; i < 4; ++i) {
      int gnb = n0 + wr + i * 16 + quad * 4;
      float4 bi = *(const float4*)(bias + gnb);
      const int nl = wr + i * 16 + quad * 4;
      for (int j = 0; j < 4; ++j) {
        const int ml = wc + j * 16 + col;
        bf16x4 pk;
        pk[0] = (__bf16)((acc[i][j][0] + bi.x) * scale);
        pk[1] = (__bf16)((acc[i][j][1] + bi.y) * scale);
        pk[2] = (__bf16)((acc[i][j][2] + bi.z) * scale);
        pk[3] = (__bf16)((acc[i][j][3] + bi.w) * scale);
        *(bf16x4*)(epi + (size_t)ml * PITCH + nl) = pk;
      }
    }
    __syncthreads();
    __bf16* dst = (z == 0) ? qh : kh;
    const int b = m0 >> 11;
    const int h0 = n0 >> 6;
    const int sb = m0 & 2047;
    for (int kk = 0; kk < 8; ++kk) {
      int g = kk * 32 + (t >> 3);
      int h2 = g >> 7, sl2 = g & 127;
      int cc = t & 7;
      bf16x8 v = *(const bf16x8*)(epi + (size_t)sl2 * PITCH + h2 * 64 + cc * 8);
      *(bf16x8*)(dst + ((size_t)(b * H_ + h0 + h2) * S_ + sb + sl2) * HD_ +
                 cc * 8) = v;
    }
  } else {
    for (int kt = 0; kt < NIT; ++kt) {
      const int cur = kt & 1;
      __syncthreads();
      if (kt + 1 < NIT) stage(kt + 1, cur ^ 1);
      bf16x8 fx[4], fw[4];
      for (int i = 0; i < 4; ++i) {
        int m = wr + i * 16 + col;
        int sl = quad ^ (m & 3);
        fx[i] = *(const bf16x8*)(lA(cur) + m * 64 + sl * 16);
      }
      for (int j = 0; j < 4; ++j) {
        int n = wc + j * 16 + col;
        int sl = quad ^ (n & 3);
        fw[j] = *(const bf16x8*)(lB(cur) + n * 64 + sl * 16);
      }
      for (int i = 0; i < 4; ++i)
        for (int j = 0; j < 4; ++j)
          acc[i][j] = __builtin_amdgcn_mfma_f32_16x16x32_bf16(
              fx[i], fw[j], acc[i][j], 0, 0, 0);
    }
    // ---- epilogue: acc -> LDS [n][m] in R9 fragment order, coalesced stores ----
    __syncthreads();
    const int quadv = ((quad & 1) << 1) | ((quad >> 1) & 1);  // R9 involution
    for (int i = 0; i < 4; ++i) {
      const int ml = wr + i * 16 + quadv * 4;  // fragment-order m slot
      for (int j = 0; j < 4; ++j) {
        int gn = n0 + wc + j * 16 + col;
        const int nl = wc + j * 16 + col;
        float bi = bias[gn];
        bf16x4 pk;
        pk[0] = (__bf16)(acc[i][j][0] + bi);
        pk[1] = (__bf16)(acc[i][j][1] + bi);
        pk[2] = (__bf16)(acc[i][j][2] + bi);
        pk[3] = (__bf16)(acc[i][j][3] + bi);
        *(bf16x4*)(epi + (size_t)nl * PITCH + ml) = pk;
      }
    }
    __syncthreads();
    const int b = m0 >> 11;
    const int sb = m0 & 2047;
    for (int kk = 0; kk < 8; ++kk) {
      int nl = kk * 16 + (t >> 4);
      int cc = t & 15;
      bf16x8 v = *(const bf16x8*)(epi + (size_t)nl * PITCH + cc * 8);
      int h = (n0 + nl) >> 6, hd = (n0 + nl) & 63;
      *(bf16x8*)(vt + ((size_t)(b * H_ + h) * HD_ + hd) * S_ + sb + cc * 8) = v;
    }
  }
}

// ---------------- attention phase 1: 64 q/wave, b128 V-fragment reads ----------------
// grid (bh=32, qblk=8, kc=2) = 512 blocks = 2/CU; XCD = bh%8 (all 16 blocks
// sharing a bh's K/V land on one XCD - already optimal).
// R11/R12-verified version (R13 anti-phase reverted).
// NOTE (R1): never cap regs at 128 (spill -> 3GB/disp scratch streamer).
// NOTE (R3): KSTEP=128 / setprio neutral. (R5): VALU cut neutral. (R7): SW
// pipeline neutral. (R8): 2x occupancy neutral. (R13): anti-phase REGRESSED.
__global__ __launch_bounds__(256, 2) void attn1(
    const __bf16* __restrict__ qh, const __bf16* __restrict__ kh,
    const __bf16* __restrict__ vt, __bf16* __restrict__ po,
    float* __restrict__ pl) {
  __shared__ __attribute__((aligned(16))) __bf16 lK[2][64 * 64];  // [sk][hd] swz
  __shared__ __attribute__((aligned(16))) __bf16 lV[2][64 * 64];  // [hd][sk-frag] swz

  const int t = threadIdx.x;
  const int lane = t & 63;
  const int half = lane >> 5;
  const int q31 = lane & 31;
  const int bh = blockIdx.x;
  const int kc = blockIdx.z;
  const int q0w = blockIdx.y * 256 + (t >> 6) * 64;  // wave's 64 q rows

  const __bf16* qbase = qh + (size_t)bh * S_ * HD_;
  const __bf16* kbase = kh + (size_t)bh * S_ * HD_;
  const __bf16* vbase = vt + (size_t)bh * HD_ * S_;

  // Q as B-frags: B[n=q=lane&31][k=16ks+8*half+j], per q-tile
  bf16x8 aq[2][4];
  for (int qt = 0; qt < 2; ++qt)
    for (int ks = 0; ks < 4; ++ks)
      aq[qt][ks] = *(const bf16x8*)(qbase +
          (size_t)(q0w + qt * 32 + q31) * HD_ + ks * 16 + half * 8);

  f32x16 o[2][2] = {};  // [qt][hdt]
  f32x2 ls[2] = {{0.f, 0.f}, {0.f, 0.f}};

  const int srow = t >> 3;                  // 0..31
  const int sgc = (t & 7) ^ (srow & 7);     // swizzled global chunk

  auto stage = [&](int kt, int buf) {
    gload16(kbase + (size_t)(kt * 64 + srow) * HD_ + sgc * 8,
            (char*)&lK[buf][0] + t * 16);
    gload16(kbase + (size_t)(kt * 64 + 32 + srow) * HD_ + sgc * 8,
            (char*)&lK[buf][0] + 4096 + t * 16);
    gload16(vbase + (size_t)srow * S_ + kt * 64 + sgc * 8,
            (char*)&lV[buf][0] + t * 16);
    gload16(vbase + (size_t)(32 + srow) * S_ + kt * 64 + sgc * 8,
            (char*)&lV[buf][0] + 4096 + t * 16);
  };

  stage(kc * 16, 0);

  for (int kt0 = 0; kt0 < 16; ++kt0) {
    const int cur = kt0 & 1;
    __syncthreads();  // drains vmcnt: buf[cur] staged; all done reading buf[cur^1]
    if (kt0 + 1 < 16) stage(kc * 16 + kt0 + 1, cur ^ 1);

    // ---- hoisted LDS reads: everything this iteration needs ----
    bf16x8 fk[2][4];       // [st][ks]
    bf16x8 av[2][2][2];    // [st][hdt][k2] V^T A-frags (b128, frag-ordered vt)
#pragma unroll
    for (int st = 0; st < 2; ++st) {
      const int row = st * 32 + q31;
#pragma unroll
      for (int ks = 0; ks < 4; ++ks) {
        int pos = (2 * ks + half) ^ (row & 7);
        fk[st][ks] = *(const bf16x8*)((const char*)&lK[cur][0] + row * 128 + pos * 16);
      }
    }
#pragma unroll
    for (int st = 0; st < 2; ++st)
#pragma unroll
      for (int hdt = 0; hdt < 2; ++hdt) {
        const int rowv = hdt * 32 + q31;
#pragma unroll
        for (int k2 = 0; k2 < 2; ++k2) {
          int pos = (st * 4 + k2 * 2 + half) ^ (rowv & 7);
          av[st][hdt][k2] = *(const bf16x8*)((const char*)&lV[cur][0] + rowv * 128 +
                                             pos * 16);
        }
      }

#pragma unroll
    for (int st = 0; st < 2; ++st) {
      // S^T tiles for both q-tiles; each fk feeds two MFMAs
      f32x16 sc0 = {}, sc1 = {};
#pragma unroll
      for (int ks = 0; ks < 4; ++ks) {
        sc0 = __builtin_amdgcn_mfma_f32_32x32x16_bf16(fk[st][ks], aq[0][ks], sc0, 0, 0, 0);
        sc1 = __builtin_amdgcn_mfma_f32_32x32x16_bf16(fk[st][ks], aq[1][ks], sc1, 0, 0, 0);
      }

      // exp2 + packed lsum + pack pairs via v_perm (round-half-up), per q-tile
      uint32_t pk0[8], pk1[8];
#pragma unroll
      for (int p = 0; p < 8; ++p) {
        float ea = __builtin_amdgcn_exp2f(sc0[2 * p]);
        float eb = __builtin_amdgcn_exp2f(sc0[2 * p + 1]);
        f32x2 e2 = {ea, eb};
        ls[0] += e2;
        uint32_t au = __builtin_bit_cast(uint32_t, ea) + 0x8000u;
        uint32_t bu = __builtin_bit_cast(uint32_t, eb) + 0x8000u;
        pk0[p] = __builtin_amdgcn_perm(bu, au, 0x07060302u);
      }
#pragma unroll
      for (int p = 0; p < 8; ++p) {
        float ea = __builtin_amdgcn_exp2f(sc1[2 * p]);
        float eb = __builtin_amdgcn_exp2f(sc1[2 * p + 1]);
        f32x2 e2 = {ea, eb};
        ls[1] += e2;
        uint32_t au = __builtin_bit_cast(uint32_t, ea) + 0x8000u;
        uint32_t bu = __builtin_bit_cast(uint32_t, eb) + 0x8000u;
        pk1[p] = __builtin_amdgcn_perm(bu, au, 0x07060302u);
      }

      // P B-frags, K=16 (k-map k(h,j) = 8*(j>>2) + 4h + (j&3), matches av)
      u32x4 w;
      w[0] = pk0[0]; w[1] = pk0[1]; w[2] = pk0[2]; w[3] = pk0[3];
      bf16x8 fp0a = __builtin_bit_cast(bf16x8, w);
      w[0] = pk0[4]; w[1] = pk0[5]; w[2] = pk0[6]; w[3] = pk0[7];
      bf16x8 fp0b = __builtin_bit_cast(bf16x8, w);
      w[0] = pk1[0]; w[1] = pk1[1]; w[2] = pk1[2]; w[3] = pk1[3];
      bf16x8 fp1a = __builtin_bit_cast(bf16x8, w);
      w[0] = pk1[4]; w[1] = pk1[5]; w[2] = pk1[6]; w[3] = pk1[7];
      bf16x8 fp1b = __builtin_bit_cast(bf16x8, w);

      // O^T += V^T · P^T, K=16 per MFMA (av read directly from LDS, no concat)
#pragma unroll
      for (int hdt = 0; hdt < 2; ++hdt) {
        o[0][hdt] = __builtin_amdgcn_mfma_f32_32x32x16_bf16(av[st][hdt][0], fp0a, o[0][hdt], 0, 0, 0);
        o[1][hdt] = __builtin_amdgcn_mfma_f32_32x32x16_bf16(av[st][hdt][0], fp1a, o[1][hdt], 0, 0, 0);
        o[0][hdt] = __builtin_amdgcn_mfma_f32_32x32x16_bf16(av[st][hdt][1], fp0b, o[0][hdt], 0, 0, 0);
        o[1][hdt] = __builtin_amdgcn_mfma_f32_32x32x16_bf16(av[st][hdt][1], fp1b, o[1][hdt], 0, 0, 0);
      }
    }
  }

  // store partials per q-tile: po[(kc*32+bh)][qrow][hd] bf16 (8B), pl fp32
  const size_t slab = (size_t)(kc * 32 + bh) * S_;
  for (int qt = 0; qt < 2; ++qt) {
    float lq = ls[qt].x + ls[qt].y;
    float ltot = lq + __shfl_xor(lq, 32);
    const int qrow = q0w + qt * 32 + q31;
    if (half == 0) pl[slab + qrow] = ltot;
    for (int hdt = 0; hdt < 2; ++hdt)
      for (int rq = 0; rq < 4; ++rq) {
        bf16x4 pk;
        pk[0] = (__bf16)o[qt][hdt][rq * 4 + 0];
        pk[1] = (__bf16)o[qt][hdt][rq * 4 + 1];
        pk[2] = (__bf16)o[qt][hdt][rq * 4 + 2];
        pk[3] = (__bf16)o[qt][hdt][rq * 4 + 3];
        *(bf16x4*)(po + (slab + qrow) * HD_ + hdt * 32 + rq * 8 + half * 4) = pk;
      }
  }
}

// ---------------- attention phase 2: combine, divide, mean-pool ----------------
// grid (rg=32, bh=32) = 1024 blocks. R13-verified: bf16x2 loads, 2 hd/thread.
__global__ __launch_bounds__(256) void attn2(const __bf16* __restrict__ po,
                                             const float* __restrict__ pl,
                                             float* __restrict__ out) {
  __shared__ f32x2 red[256];
  const int t = threadIdx.x;
  const int hd2 = (t & 31) * 2;
  const int rgrp = t >> 5;   // 0..7
  const int bh = blockIdx.y;
  const int r0 = blockIdx.x * 64 + rgrp * 8;
  const size_t s0 = (size_t)bh * S_;
  const size_t s1 = (size_t)(32 + bh) * S_;
  f32x2 acc = {0.f, 0.f};
#pragma unroll 8
  for (int i = 0; i < 8; ++i) {
    int row = r0 + i;
    float l = pl[s0 + row] + pl[s1 + row];
    bf16x2 a = *(const bf16x2*)(po + (s0 + row) * HD_ + hd2);
    bf16x2 b = *(const bf16x2*)(po + (s1 + row) * HD_ + hd2);
    acc.x += ((float)a[0] + (float)b[0]) / l;
    acc.y += ((float)a[1] + (float)b[1]) / l;
  }
  red[t] = acc;
  __syncthreads();
  if (t < 32) {
    f32x2 s = red[t];
#pragma unroll
    for (int g = 1; g < 8; ++g) s += red[t + g * 32];
    float* ob = out + (size_t)(bh >> 4) * D_ + (bh & 15) * HD_ + hd2;
    atomicAdd(ob,     s.x * (1.0f / S_));
    atomicAdd(ob + 1, s.y * (1.0f / S_));
  }
}

extern "C" void kernel_launch(void* const* d_in, const int* in_sizes, int n_in,
                              void* d_out, int out_size, void* d_ws, size_t ws_size,
                              hipStream_t stream) {
  const float* x  = (const float*)d_in[0];
  const float* Wq = (const float*)d_in[1];
  const float* bq = (const float*)d_in[2];
  const float* Wk = (const float*)d_in[3];
  const float* bk = (const float*)d_in[4];
  const float* Wv = (const float*)d_in[5];
  const float* bv = (const float*)d_in[6];
  float* out = (float*)d_out;

  char* ws = (char*)d_ws;
  __bf16* qh = (__bf16*)(ws);                       //  0..8 MB
  __bf16* kh = (__bf16*)(ws + ((size_t)8  << 20));  //  8..16 MB
  __bf16* vt = (__bf16*)(ws + ((size_t)16 << 20));  // 16..24 MB
  __bf16* xb = (__bf16*)(ws + ((size_t)24 << 20));  // 24..32 MB (dead after gemm)
  __bf16* wt = (__bf16*)(ws + ((size_t)32 << 20));  // 32..38 MB (dead after gemm)
  __bf16* po = (__bf16*)(ws + ((size_t)24 << 20));  // 24..40 MB (overlays xb/wt)
  float*  pl = (float*) (ws + ((size_t)40 << 20));  // 40..40.5 MB

  prep<<<dim3(7169), dim3(256), 0, stream>>>(x, Wq, Wk, Wv, xb, wt, out);
  gemm_qkv<<<dim3(768), dim3(256), 0, stream>>>(xb, wt, bq, bk, bv, qh, kh, vt);
  attn1<<<dim3(B_ * H_, 8, 2), dim3(256), 0, stream>>>(qh, kh, vt, po, pl);
  attn2<<<dim3(32, B_ * H_), dim3(256), 0, stream>>>(po, pl, out);
}